// Round 7
// baseline (256.569 us; speedup 1.0000x reference)
//
#include <hip/hip_runtime.h>
#include <hip/hip_bf16.h>

typedef __attribute__((ext_vector_type(8))) short bf16x8;
typedef __attribute__((ext_vector_type(4))) float f32x4;
typedef unsigned short u16;

#define S_LEN 4096
#define DM 1024
#define NH 16
#define DH 64
#define PSTR 72

// manual RNE fp32->bf16 (inputs never NaN here): 3 VALU ops
__device__ __forceinline__ u16 f2b_rne(float f) {
  unsigned u = __builtin_bit_cast(unsigned, f);
  return (u16)((u + 0x7fffu + ((u >> 16) & 1u)) >> 16);
}
// pack two fp32 -> bf16x2 in one u32 (RNE)
__device__ __forceinline__ unsigned pk2(float a, float b) {
  unsigned ua = __builtin_bit_cast(unsigned, a);
  unsigned ub = __builtin_bit_cast(unsigned, b);
  ua = (ua + 0x7fffu + ((ua >> 16) & 1u)) >> 16;
  ub = (ub + 0x7fffu + ((ub >> 16) & 1u)) & 0xffff0000u;
  return ua | ub;
}
// pack two fp32 -> bf16x2, TRUNCATED: single v_perm_b32.
// bias cancels in softmax (same P in numerator and denominator).
__device__ __forceinline__ unsigned pk2t(float a, float b) {
  return __builtin_amdgcn_perm(__builtin_bit_cast(unsigned, b),
                               __builtin_bit_cast(unsigned, a), 0x07060302u);
}

// global -> LDS direct (16B per lane; lds base must be wave-uniform)
__device__ __forceinline__ void glds16(const u16* g, u16* l) {
  __builtin_amdgcn_global_load_lds(
      (const __attribute__((address_space(1))) unsigned int*)g,
      (__attribute__((address_space(3))) unsigned int*)l, 16, 0, 0);
}

// ---------------- fp32 -> bf16, all 5 inputs in one launch ----------------
__global__ __launch_bounds__(256) void cvt_all(const float* __restrict__ x,
                                               const float* __restrict__ Wq,
                                               const float* __restrict__ Wk,
                                               const float* __restrict__ Wv,
                                               const float* __restrict__ Wo,
                                               u16* __restrict__ xb, u16* __restrict__ wqb,
                                               u16* __restrict__ wkb, u16* __restrict__ wvb,
                                               u16* __restrict__ wob) {
  int idx = (blockIdx.x * 256 + threadIdx.x) * 4;
  const float* src;
  u16* dst;
  int o;
  if (idx < 4194304) {
    src = x; dst = xb; o = idx;
  } else {
    int t = idx - 4194304;
    int wsel = t >> 20;
    o = t & 1048575;
    src = (wsel == 0) ? Wq : (wsel == 1) ? Wk : (wsel == 2) ? Wv : Wo;
    dst = (wsel == 0) ? wqb : (wsel == 1) ? wkb : (wsel == 2) ? wvb : wob;
  }
  float4 v = *(const float4*)(src + o);
  uint2 ov;
  ov.x = pk2(v.x, v.y);
  ov.y = pk2(v.z, v.w);
  *(uint2*)(dst + o) = ov;
}

// ---------------- zero the O/L accumulators (16 MB + 256 KB) ---------------
__global__ __launch_bounds__(256) void zero_kernel(float4* __restrict__ p) {
  p[blockIdx.x * 256 + threadIdx.x] = float4{0.f, 0.f, 0.f, 0.f};
}

// ---------------- fused QKV NT-GEMM with RoPE epilogue; V written transposed
// grid (24, 32): mat = bx>>3 (0=Q rope+scale, 1=K rope, 2=V -> Vt), nb = (bx&7)*128
__global__ __launch_bounds__(256) void qkv_gemm(const u16* __restrict__ A,
                                                const u16* __restrict__ Wq,
                                                const u16* __restrict__ Wk,
                                                const u16* __restrict__ Wv,
                                                u16* __restrict__ Qo, u16* __restrict__ Ko,
                                                u16* __restrict__ Vt) {
  __shared__ __align__(16) u16 As[2 * 128 * 32];
  __shared__ __align__(16) u16 Bs[2 * 128 * 32];
  const int mat = blockIdx.x >> 3;
  const u16* B = (mat == 0) ? Wq : (mat == 1) ? Wk : Wv;
  const int K = DM, N = DM;
  const int tid = threadIdx.x;
  const int wave = tid >> 6, lane = tid & 63;
  const int fm = lane & 15, fq = lane >> 4;
  const int mb = blockIdx.y * 128, nb = (blockIdx.x & 7) * 128;
  const int wm = (wave & 1) * 64, wn = (wave >> 1) * 64;

  f32x4 acc[4][4];
#pragma unroll
  for (int i = 0; i < 4; ++i)
#pragma unroll
    for (int j = 0; j < 4; ++j)
#pragma unroll
      for (int r = 0; r < 4; ++r) acc[i][j][r] = 0.f;

  const int r_ = tid >> 2;
  const int cg = (tid & 3) ^ ((r_ >> 1) & 3);
  const u16* Ag0 = A + (size_t)(mb + r_) * K + cg * 8;
  const u16* Ag1 = A + (size_t)(mb + r_ + 64) * K + cg * 8;
  const u16* Bg0 = B + (size_t)(nb + r_) * K + cg * 8;
  const u16* Bg1 = B + (size_t)(nb + r_ + 64) * K + cg * 8;
  const int l0 = wave * 512;
  const int l1 = 2048 + wave * 512;
  const int sw = (fm >> 1) & 3;

  int buf = 0;
  glds16(Ag0, As + l0);
  glds16(Ag1, As + l1);
  glds16(Bg0, Bs + l0);
  glds16(Bg1, Bs + l1);

  for (int k0 = 0; k0 < K; k0 += 32) {
    __syncthreads();
    if (k0 + 32 < K) {
      int bo = (buf ^ 1) * 4096;
      glds16(Ag0 + k0 + 32, As + bo + l0);
      glds16(Ag1 + k0 + 32, As + bo + l1);
      glds16(Bg0 + k0 + 32, Bs + bo + l0);
      glds16(Bg1 + k0 + 32, Bs + bo + l1);
    }
    const u16* Ab = As + buf * 4096;
    const u16* Bb = Bs + buf * 4096;
    bf16x8 av[4], bv[4];
#pragma unroll
    for (int t = 0; t < 4; ++t) {
      av[t] = *(const bf16x8*)(Ab + (wm + t * 16 + fm) * 32 + ((fq ^ sw) * 8));
      bv[t] = *(const bf16x8*)(Bb + (wn + t * 16 + fm) * 32 + ((fq ^ sw) * 8));
    }
#pragma unroll
    for (int i = 0; i < 4; ++i)
#pragma unroll
      for (int j = 0; j < 4; ++j)
        acc[i][j] = __builtin_amdgcn_mfma_f32_16x16x32_bf16(av[i], bv[j], acc[i][j], 0, 0, 0);
    buf ^= 1;
  }

  if (mat < 2) {
    // RoPE epilogue (in-register): pairs (d, d+32) = regs (j, j+2), d = j*16+fm, j in {0,1}
    u16* Out = (mat == 0) ? Qo : Ko;
    const float qs = (mat == 0) ? 0.1803368801111204f : 1.0f;  // 0.125*log2(e) for Q
    const float c1 = -9.2103403719761836f / 32.f;              // -ln(10000)/32
    const float if0 = __expf((float)fm * c1);
    const float if1 = __expf((float)(16 + fm) * c1);
#pragma unroll
    for (int ii = 0; ii < 4; ++ii) {
#pragma unroll
      for (int r = 0; r < 4; ++r) {
        float s = (float)(mb + wm + ii * 16 + fq * 4 + r);
#pragma unroll
        for (int jp = 0; jp < 2; ++jp) {
          float ang = s * (jp ? if1 : if0);
          float sn, cs;
          __sincosf(ang, &sn, &cs);
          float a = acc[ii][jp][r], b = acc[ii][jp + 2][r];
          acc[ii][jp][r] = (a * cs - b * sn) * qs;
          acc[ii][jp + 2][r] = (b * cs + a * sn) * qs;
        }
      }
    }
#pragma unroll
    for (int i = 0; i < 4; ++i)
#pragma unroll
      for (int j = 0; j < 4; ++j)
#pragma unroll
        for (int r = 0; r < 4; ++r) {
          int row = mb + wm + i * 16 + fq * 4 + r;
          int col = nb + wn + j * 16 + fm;
          Out[(size_t)row * N + col] = f2b_rne(acc[i][j][r]);
        }
  } else {
    // V: write transposed Vt[col][row]; 4 r-values are contiguous rows -> 8B store
#pragma unroll
    for (int i = 0; i < 4; ++i)
#pragma unroll
      for (int j = 0; j < 4; ++j) {
        int col = nb + wn + j * 16 + fm;
        int row0 = mb + wm + i * 16 + fq * 4;
        uint2 pv;
        pv.x = pk2(acc[i][j][0], acc[i][j][1]);
        pv.y = pk2(acc[i][j][2], acc[i][j][3]);
        *(uint2*)(Vt + (size_t)col * S_LEN + row0) = pv;
      }
  }
}

// ---------------- O-projection GEMM fused with combine ----------------------
// A[row][k] = Oacc[k>>6][row][k&63] / Lacc[k>>6][row]; C = A @ Wo^T (fp32).
// A staged via VGPR (normalize + RNE pack + ds_write); B via glds16.
// K-loop fully unrolled so the head index (k>>6) is compile-time.
__global__ __launch_bounds__(256) void o_gemm(const float* __restrict__ Oacc,
                                              const float* __restrict__ Lacc,
                                              const u16* __restrict__ B,
                                              float* __restrict__ C) {
  __shared__ __align__(16) u16 As[2 * 64 * 32];
  __shared__ __align__(16) u16 Bs[2 * 128 * 32];
  const int tid = threadIdx.x;
  const int wave = tid >> 6, lane = tid & 63;
  const int fm = lane & 15, fq = lane >> 4;
  const int mb = blockIdx.y * 64, nb = blockIdx.x * 128;
  const int wm = (wave & 1) * 32, wn = (wave >> 1) * 64;

  f32x4 acc[2][4];
#pragma unroll
  for (int i = 0; i < 2; ++i)
#pragma unroll
    for (int j = 0; j < 4; ++j)
#pragma unroll
      for (int r = 0; r < 4; ++r) acc[i][j][r] = 0.f;

  const int r_ = tid >> 2;
  const int cg = (tid & 3) ^ ((r_ >> 1) & 3);
  const int arow = mb + r_;
  // per-lane inverse l for all 16 heads (row is fixed per lane)
  float il[16];
#pragma unroll
  for (int hh = 0; hh < 16; ++hh) il[hh] = 1.0f / Lacc[hh * S_LEN + arow];

  const u16* Bg0 = B + (size_t)(nb + r_) * DM + cg * 8;
  const u16* Bg1 = B + (size_t)(nb + r_ + 64) * DM + cg * 8;
  const int l0 = wave * 512;
  const int l1 = 2048 + wave * 512;
  const int sw = (fm >> 1) & 3;
  const int awr = r_ * 32 + (tid & 3) * 8;  // A ds_write offset (matches glds16 map)

  int buf = 0;
  glds16(Bg0, Bs + l0);
  glds16(Bg1, Bs + l1);
  // A tile 0 (k0=0 -> h=0, d = cg*8)
  float4 a0 = *(const float4*)(Oacc + (size_t)arow * 64 + cg * 8);
  float4 a1 = *(const float4*)(Oacc + (size_t)arow * 64 + cg * 8 + 4);

#pragma unroll
  for (int k0 = 0; k0 < DM; k0 += 32) {
    // stage A_k (in VGPRs) into LDS, normalized + RNE-packed
    const float ih = il[k0 >> 6];
    uint4 aw;
    aw.x = pk2(a0.x * ih, a0.y * ih);
    aw.y = pk2(a0.z * ih, a0.w * ih);
    aw.z = pk2(a1.x * ih, a1.y * ih);
    aw.w = pk2(a1.z * ih, a1.w * ih);
    *(uint4*)(As + buf * 2048 + awr) = aw;
    __syncthreads();  // drains B glds for this tile; A ds_writes visible
    if (k0 + 32 < DM) {
      int bo = (buf ^ 1) * 4096;
      glds16(Bg0 + k0 + 32, Bs + bo + l0);
      glds16(Bg1 + k0 + 32, Bs + bo + l1);
      const float* ap = Oacc + ((size_t)((k0 + 32) >> 6) * S_LEN + arow) * 64 +
                        ((k0 + 32) & 63) + cg * 8;
      a0 = *(const float4*)(ap);
      a1 = *(const float4*)(ap + 4);
    }
    const u16* Ab = As + buf * 2048;
    const u16* Bb = Bs + buf * 4096;
    bf16x8 av[2], bv[4];
#pragma unroll
    for (int t = 0; t < 2; ++t)
      av[t] = *(const bf16x8*)(Ab + (wm + t * 16 + fm) * 32 + ((fq ^ sw) * 8));
#pragma unroll
    for (int t = 0; t < 4; ++t)
      bv[t] = *(const bf16x8*)(Bb + (wn + t * 16 + fm) * 32 + ((fq ^ sw) * 8));
#pragma unroll
    for (int i = 0; i < 2; ++i)
#pragma unroll
      for (int j = 0; j < 4; ++j)
        acc[i][j] = __builtin_amdgcn_mfma_f32_16x16x32_bf16(av[i], bv[j], acc[i][j], 0, 0, 0);
    buf ^= 1;
  }
#pragma unroll
  for (int i = 0; i < 2; ++i)
#pragma unroll
    for (int j = 0; j < 4; ++j)
#pragma unroll
      for (int r = 0; r < 4; ++r) {
        int row = mb + wm + i * 16 + fq * 4 + r;
        int col = nb + wn + j * 16 + fm;
        C[(size_t)row * DM + col] = acc[i][j][r];
      }
}

// ---------------- causal flash attention v7: 4-way split, balanced grid -----
// 512 threads / 8 waves, 256 q-rows per block. T(qt) = 4qt+4 tiles split
// exactly into 4 quarters of (qt+1). Grid 1024, rotation-balanced mapping:
// every CU's 4 blocks (round-robin) sum to exactly 34 tiles, LPT order
// (qt=15 first); bid&7 = h&7 -> 2 heads per XCD (K/V L2 locality; all 4
// quarter-writers of an (h,qt) share an XCD for atomic locality).
__global__ __launch_bounds__(512, 4) void attn_kernel(const u16* __restrict__ Q,
                                                      const u16* __restrict__ K,
                                                      const u16* __restrict__ Vt,
                                                      float* __restrict__ Oacc,
                                                      float* __restrict__ Lacc) {
  __shared__ __align__(16) u16 Ks[2 * 4096];   // 2 x (64 key x 64 d), swizzled
  __shared__ __align__(16) u16 Vs[2 * 4096];   // 2 x (64 d x 64 key), swizzled
  __shared__ __align__(16) u16 Ps[8][16 * PSTR];  // per-wave, g-sequential
  const int tid = threadIdx.x;
  const int w = tid >> 6, lane = tid & 63;
  const int fm = lane & 15, fq = lane >> 4;
  const int bid = blockIdx.x;            // [0,1024)
  const int p = bid >> 3, hl = bid & 7;
  const int r4 = p >> 5, jj = (p >> 3) & 3;
  const int quarter = (p >> 1) & 3, hh = p & 1;
  const int qt = 15 - (4 * r4 + ((jj + r4) & 3));
  const int h = hh * 8 + hl;
  const int qb = qt * 256 + w * 32;
  const int nlocal = qt + 1;             // tiles for this quarter
  const int kbase = quarter * nlocal;
  const int dtile = qb >> 6;             // == dtile: partial mask; > dtile: skip

  bf16x8 q0[2], q1[2];
#pragma unroll
  for (int g = 0; g < 2; ++g) {
    const u16* qp = Q + (size_t)(qb + g * 16 + fm) * DM + h * DH + fq * 8;
    q0[g] = *(const bf16x8*)(qp);
    q1[g] = *(const bf16x8*)(qp + 32);
  }
  f32x4 o[2][4];
  f32x4 ls[2];
#pragma unroll
  for (int g = 0; g < 2; ++g) {
#pragma unroll
    for (int r = 0; r < 4; ++r) ls[g][r] = 0.f;
#pragma unroll
    for (int c4 = 0; c4 < 4; ++c4)
#pragma unroll
      for (int r = 0; r < 4; ++r) o[g][c4][r] = 0.f;
  }
  const short ONEB = (short)0x3F80;  // 1.0 bf16
  const bf16x8 vone = {ONEB, ONEB, ONEB, ONEB, ONEB, ONEB, ONEB, ONEB};

  // staging: 512 slots x 16B = one full 64x64 tile; slot = tid.
  const int rr = tid >> 3;                 // [0,64)
  const int cc8 = (tid & 7) ^ (rr & 7);
  const u16* Kg = K + (size_t)rr * DM + h * DH + cc8 * 8;
  const u16* Vg = Vt + (size_t)(h * DH + rr) * S_LEN + cc8 * 8;
  const int l0 = w * 512;                  // wave-uniform LDS base (u16)
  const int sw7 = fm & 7;
  const f32x4 zf = {0.f, 0.f, 0.f, 0.f};

  glds16(Kg + (size_t)kbase * 64 * DM, Ks + l0);
  glds16(Vg + kbase * 64, Vs + l0);

  int buf = 0;
  for (int kl = 0; kl < nlocal; ++kl) {
    const int ktg = kbase + kl;
    __syncthreads();
    if (kl + 1 < nlocal) {
      int bo = (buf ^ 1) * 4096;
      glds16(Kg + (size_t)(ktg + 1) * 64 * DM, Ks + bo + l0);
      glds16(Vg + (ktg + 1) * 64, Vs + bo + l0);
    }
    if (ktg <= dtile) {
      const u16* Kb = Ks + buf * 4096;
      const u16* Vb = Vs + buf * 4096;

      // S^T = K * Q^T : D[key][q]
      f32x4 st[2][4];
#pragma unroll
      for (int t = 0; t < 4; ++t) {
        const u16* kr = Kb + (t * 16 + fm) * 64;
        bf16x8 ka = *(const bf16x8*)(kr + ((fq ^ sw7) * 8));
        bf16x8 kb2 = *(const bf16x8*)(kr + (((fq + 4) ^ sw7) * 8));
#pragma unroll
        for (int g = 0; g < 2; ++g) {
          f32x4 s = __builtin_amdgcn_mfma_f32_16x16x32_bf16(ka, q0[g], zf, 0, 0, 0);
          st[g][t] = __builtin_amdgcn_mfma_f32_16x16x32_bf16(kb2, q1[g], s, 0, 0, 0);
        }
      }
      if (ktg == dtile) {  // diagonal tile: partial causal mask
#pragma unroll
        for (int g = 0; g < 2; ++g) {
          int qg = qb + g * 16 + fm;
#pragma unroll
          for (int t = 0; t < 4; ++t) {
            int key = ktg * 64 + t * 16 + fq * 4;
#pragma unroll
            for (int r = 0; r < 4; ++r)
              st[g][t][r] = (key + r > qg) ? -1e30f : st[g][t][r];
          }
        }
      }
      // V B-operand fragments (shared across g)
      bf16x8 pvb[4][2];
#pragma unroll
      for (int c4 = 0; c4 < 4; ++c4) {
        const u16* vr = Vb + (c4 * 16 + fm) * 64;
        pvb[c4][0] = *(const bf16x8*)(vr + ((fq ^ sw7) * 8));
        pvb[c4][1] = *(const bf16x8*)(vr + (((fq + 4) ^ sw7) * 8));
      }
      // g-sequential: exp2 -> pack -> LDS -> A-frag -> MFMAs
#pragma unroll
      for (int g = 0; g < 2; ++g) {
#pragma unroll
        for (int t = 0; t < 4; ++t) {
          float p0 = __builtin_amdgcn_exp2f(st[g][t][0]);
          float p1 = __builtin_amdgcn_exp2f(st[g][t][1]);
          float p2 = __builtin_amdgcn_exp2f(st[g][t][2]);
          float p3 = __builtin_amdgcn_exp2f(st[g][t][3]);
          uint2 pk;
          pk.x = pk2t(p0, p1);
          pk.y = pk2t(p2, p3);
          *(uint2*)(&Ps[w][fm * PSTR + t * 16 + fq * 4]) = pk;
        }
        asm volatile("s_waitcnt lgkmcnt(0)" ::: "memory");
        bf16x8 ap0 = *(const bf16x8*)(&Ps[w][fm * PSTR + fq * 8]);
        bf16x8 ap1 = *(const bf16x8*)(&Ps[w][fm * PSTR + 32 + fq * 8]);
        ls[g] = __builtin_amdgcn_mfma_f32_16x16x32_bf16(ap0, vone, ls[g], 0, 0, 0);
        ls[g] = __builtin_amdgcn_mfma_f32_16x16x32_bf16(ap1, vone, ls[g], 0, 0, 0);
#pragma unroll
        for (int c4 = 0; c4 < 4; ++c4) {
          o[g][c4] = __builtin_amdgcn_mfma_f32_16x16x32_bf16(ap0, pvb[c4][0], o[g][c4], 0, 0, 0);
          o[g][c4] = __builtin_amdgcn_mfma_f32_16x16x32_bf16(ap1, pvb[c4][1], o[g][c4], 0, 0, 0);
        }
      }
    }
    buf ^= 1;
  }
  // accumulate partials: Oacc[h][row][d], Lacc[h][row]; ls rows = o rows = fq*4+r
  float* Ob = Oacc + ((size_t)h * S_LEN + qt * 256 + w * 32) * DH;
  float* Lb = Lacc + h * S_LEN + qt * 256 + w * 32;
#pragma unroll
  for (int g = 0; g < 2; ++g) {
    if (fm == 0) {
#pragma unroll
      for (int r = 0; r < 4; ++r)
        unsafeAtomicAdd(Lb + g * 16 + fq * 4 + r, ls[g][r]);
    }
#pragma unroll
    for (int c4 = 0; c4 < 4; ++c4)
#pragma unroll
      for (int r = 0; r < 4; ++r)
        unsafeAtomicAdd(Ob + (g * 16 + fq * 4 + r) * DH + c4 * 16 + fm, o[g][c4][r]);
  }
}

extern "C" void kernel_launch(void* const* d_in, const int* in_sizes, int n_in,
                              void* d_out, int out_size, void* d_ws, size_t ws_size,
                              hipStream_t stream) {
  const float* x  = (const float*)d_in[0];
  const float* Wq = (const float*)d_in[1];
  const float* Wk = (const float*)d_in[2];
  const float* Wv = (const float*)d_in[3];
  const float* Wo = (const float*)d_in[4];
  float* out = (float*)d_out;

  const size_t MB = 1u << 20;
  char* ws = (char*)d_ws;
  // region [0, 16.25 MB): phase 1 = xb(8) + wqb/wkb/wvb(2+2+2); phase 2 = Oacc(16)+Lacc(0.25)
  u16* xb    = (u16*)(ws + 0 * MB);
  u16* wqb   = (u16*)(ws + 8 * MB);
  u16* wkb   = (u16*)(ws + 10 * MB);
  u16* wvb   = (u16*)(ws + 12 * MB);
  float* Oacc = (float*)(ws + 0 * MB);
  float* Lacc = (float*)(ws + 16 * MB);
  u16* wob   = (u16*)(ws + 17 * MB);  // persists to o_gemm
  u16* Qb    = (u16*)(ws + 19 * MB);
  u16* Kb    = (u16*)(ws + 27 * MB);
  u16* Vtb   = (u16*)(ws + 35 * MB);

  cvt_all<<<8192, 256, 0, stream>>>(x, Wq, Wk, Wv, Wo, xb, wqb, wkb, wvb, wob);
  qkv_gemm<<<dim3(24, 32), 256, 0, stream>>>(xb, wqb, wkb, wvb, Qb, Kb, Vtb);
  zero_kernel<<<4160, 256, 0, stream>>>((float4*)Oacc);  // zeros Oacc+Lacc (16.25 MB)
  attn_kernel<<<1024, 512, 0, stream>>>(Qb, Kb, Vtb, Oacc, Lacc);
  o_gemm<<<dim3(8, 64), 256, 0, stream>>>(Oacc, Lacc, wob, out);
}